// Round 8
// baseline (436.325 us; speedup 1.0000x reference)
//
#include <hip/hip_runtime.h>
#include <cstdint>
#include <cstddef>

// ConcreteLayer forward: out = x @ softmax_rows((W + gumbel(U))/T)
// Reformulated: d_k = sum_n exp(l_kn);  out = (x .* (1/d)[k]) @ exp(l)
// B=4096, IN=4096, OUT=1024.
// Single persistent mega-kernel, 512 blocks, hand-rolled device-scope grid barriers:
//   phase A: exp-transpose tiles -> bt (bf16), atomic row-sums -> d, zero out
//   phase B: xb = bf16(x * rcp(d))
//   phase C: R5-proven GEMM (128x128 tile, TK=64, XOR-swizzled LDS, splitK=2, atomics)
// ws: xb (32MB) | bt (8MB) | dsum (16KB) | barrier counters

#define TINYF 1.17549435082228750797e-38f
#define LN2F 0.69314718055994530942f
#define LOG2EF 1.44269504088896340736f

typedef unsigned short u16;
typedef __attribute__((ext_vector_type(8))) short bf16x8;
typedef __attribute__((ext_vector_type(4))) float f32x4;

#define NBLK 512

__device__ __forceinline__ u16 f2bf(float f) {
  union { float f; uint32_t u; } v; v.f = f;
  uint32_t r = v.u + 0x7FFFu + ((v.u >> 16) & 1u);  // RNE
  return (u16)(r >> 16);
}

__device__ __forceinline__ float log2_hw(float x) { return __builtin_amdgcn_logf(x); }
__device__ __forceinline__ float exp2_hw(float x) { return __builtin_amdgcn_exp2f(x); }
__device__ __forceinline__ float rcp_hw(float x) { return __builtin_amdgcn_rcpf(x); }

__device__ __forceinline__ float gumbel_fast(float u) {   // -ln(-ln u)
  float t = -log2_hw(u);
  return -LN2F * log2_hw(t * LN2F);
}
__device__ __forceinline__ float exp_fast(float x) { return exp2_hw(x * LOG2EF); }

__device__ __forceinline__ void gld_lds16(const void* g, void* l) {
  __builtin_amdgcn_global_load_lds(
      (__attribute__((address_space(1))) void*)(g),
      (__attribute__((address_space(3))) void*)(l), 16, 0, 0);
}

// device-scope grid barrier: release fence + agent atomic arrive + spin + acquire fence
__device__ __forceinline__ void grid_barrier(unsigned* counter) {
  __syncthreads();
  if (threadIdx.x == 0) {
    __threadfence();  // release: all prior global writes visible at device scope
    __hip_atomic_fetch_add(counter, 1u, __ATOMIC_ACQ_REL, __HIP_MEMORY_SCOPE_AGENT);
    while (__hip_atomic_load(counter, __ATOMIC_ACQUIRE, __HIP_MEMORY_SCOPE_AGENT) < NBLK)
      __builtin_amdgcn_s_sleep(8);
  }
  __syncthreads();
  __threadfence();    // acquire: invalidate caches so phase-N+1 loads see fresh data
}

#define TM 128
#define TN 128
#define TK 64

__launch_bounds__(256)
__global__ void mega_kernel(const float* __restrict__ X, const float* __restrict__ W,
                            const float* __restrict__ U, const float* __restrict__ Tp,
                            u16* __restrict__ xb, u16* __restrict__ BT,
                            float* __restrict__ dsum, unsigned* __restrict__ bar,
                            float* __restrict__ C) {
  __shared__ __align__(16) char smem[32768];
  const int bid = blockIdx.x;
  const int t = threadIdx.x;

  // ---------------- phase A: exp-transpose + row sums + zero out ----------------
  {
    float (*tile)[65] = (float(*)[65])smem;
    const float invT = 1.0f / Tp[0];
    // zero d_out: 1M float4 over 512 blocks
    {
      float4 z = make_float4(0.f, 0.f, 0.f, 0.f);
      float4* out4 = (float4*)C;
#pragma unroll
      for (int j = 0; j < 8; ++j) out4[(size_t)bid * 2048 + j * 256 + t] = z;
    }
#pragma unroll
    for (int ti = 0; ti < 2; ++ti) {
      int tix = bid * 2 + ti;                  // 1024 tiles: 64 k-tiles x 16 n-tiles
      int k0 = (tix & 63) * 64, n0 = (tix >> 6) * 64;
      __syncthreads();                         // LDS reuse across iterations
      {
        const int nn4 = (t & 15) * 4, kq = t >> 4;
#pragma unroll
        for (int r = 0; r < 4; ++r) {
          int kk = r * 16 + kq;
          size_t gi = (size_t)(k0 + kk) * 1024 + (n0 + nn4);
          float4 w = *(const float4*)&W[gi];
          float4 u = *(const float4*)&U[gi];
          float e0 = exp_fast((w.x + gumbel_fast(u.x * (1.0f - TINYF) + TINYF)) * invT);
          float e1 = exp_fast((w.y + gumbel_fast(u.y * (1.0f - TINYF) + TINYF)) * invT);
          float e2 = exp_fast((w.z + gumbel_fast(u.z * (1.0f - TINYF) + TINYF)) * invT);
          float e3 = exp_fast((w.w + gumbel_fast(u.w * (1.0f - TINYF) + TINYF)) * invT);
          tile[kk][nn4 + 0] = e0; tile[kk][nn4 + 1] = e1;
          tile[kk][nn4 + 2] = e2; tile[kk][nn4 + 3] = e3;
          float s = (e0 + e1) + (e2 + e3);
#pragma unroll
          for (int m = 8; m > 0; m >>= 1) s += __shfl_xor(s, m, 16);
          if ((t & 15) == 0) atomicAdd(&dsum[k0 + kk], s);
        }
      }
      __syncthreads();
      {
        const int kk4 = (t & 15) * 4, nq = t >> 4;
#pragma unroll
        for (int r = 0; r < 4; ++r) {
          int nn = r * 16 + nq;
          ushort4 o;
          o.x = f2bf(tile[kk4 + 0][nn]);
          o.y = f2bf(tile[kk4 + 1][nn]);
          o.z = f2bf(tile[kk4 + 2][nn]);
          o.w = f2bf(tile[kk4 + 3][nn]);
          *(ushort4*)&BT[(size_t)(n0 + nn) * 4096 + (k0 + kk4)] = o;
        }
      }
    }
  }

  grid_barrier(&bar[0]);   // dsum + BT complete

  // ---------------- phase B: xb = bf16(x * rcp(d)) ----------------
  {
    const float4* x4 = (const float4*)X;
    const float4* d4 = (const float4*)dsum;
    ushort4* xb4 = (ushort4*)xb;
#pragma unroll
    for (int j = 0; j < 32; ++j) {
      int i = bid * 8192 + j * 256 + t;        // 4M float4 total
      int col4 = i & 1023;
      float4 v = x4[i];
      float4 dd = d4[col4];
      ushort4 o;
      o.x = f2bf(v.x * rcp_hw(dd.x)); o.y = f2bf(v.y * rcp_hw(dd.y));
      o.z = f2bf(v.z * rcp_hw(dd.z)); o.w = f2bf(v.w * rcp_hw(dd.w));
      xb4[i] = o;
    }
  }

  grid_barrier(&bar[1]);   // xb complete

  // ---------------- phase C: GEMM (R5 structure), splitK=2 ----------------
  {
    u16* As = (u16*)smem;            // 16 KB
    u16* Bs = (u16*)(smem + 16384);  // 16 KB

    const int lane = t & 63, w = t >> 6;
    const int wm = w >> 1, wn = w & 1;
    const int m0 = ((bid >> 3) & 31) * TM;
    const int n0 = (bid & 7) * TN;             // n-tile = bid&7 -> XCD-local bt slice
    const int kz = bid >> 8;
    const int quad = lane >> 4, r16 = lane & 15;
    const int srow = lane >> 3;
    const int sg = (lane & 7) ^ srow;

    const int Kh = 2048;
    const u16* Ak = xb + (size_t)kz * Kh;
    const u16* Bk = BT + (size_t)kz * Kh;

    f32x4 acc[4][4] = {};

    for (int kt = 0; kt < Kh; kt += TK) {
      __syncthreads();
#pragma unroll
      for (int c = 0; c < 4; ++c) {
        int chunk = w * 4 + c;
        gld_lds16(Ak + (size_t)(m0 + chunk * 8 + srow) * 4096 + kt + sg * 8, smem + chunk * 1024);
        gld_lds16(Bk + (size_t)(n0 + chunk * 8 + srow) * 4096 + kt + sg * 8, smem + 16384 + chunk * 1024);
      }
      __syncthreads();

#pragma unroll
      for (int ss = 0; ss < 2; ++ss) {
        bf16x8 aF[4], bF[4];
#pragma unroll
        for (int mi = 0; mi < 4; ++mi) {
          int row = wm * 64 + mi * 16 + r16;
          aF[mi] = *(const bf16x8*)((const char*)As + row * 128 + (((ss * 4 + quad) ^ (row & 7)) * 16));
        }
#pragma unroll
        for (int ni = 0; ni < 4; ++ni) {
          int row = wn * 64 + ni * 16 + r16;
          bF[ni] = *(const bf16x8*)((const char*)Bs + row * 128 + (((ss * 4 + quad) ^ (row & 7)) * 16));
        }
#pragma unroll
        for (int mi = 0; mi < 4; ++mi)
#pragma unroll
          for (int ni = 0; ni < 4; ++ni)
            acc[mi][ni] = __builtin_amdgcn_mfma_f32_16x16x32_bf16(aF[mi], bF[ni], acc[mi][ni], 0, 0, 0);
      }
    }

#pragma unroll
    for (int mi = 0; mi < 4; ++mi)
#pragma unroll
      for (int ni = 0; ni < 4; ++ni)
#pragma unroll
        for (int r = 0; r < 4; ++r) {
          int row = m0 + wm * 64 + mi * 16 + quad * 4 + r;
          int col = n0 + wn * 64 + ni * 16 + r16;
          atomicAdd(&C[(size_t)row * 1024 + col], acc[mi][ni][r]);
        }
  }
}

extern "C" void kernel_launch(void* const* d_in, const int* in_sizes, int n_in,
                              void* d_out, int out_size, void* d_ws, size_t ws_size,
                              hipStream_t stream) {
  const int M = 4096, K = 4096, N = 1024;  // B, IN, OUT
  const float* x = (const float*)d_in[0];
  const float* W = (const float*)d_in[1];
  const float* U = (const float*)d_in[2];
  const float* Tp = (const float*)d_in[3];
  float* out = (float*)d_out;

  char* ws = (char*)d_ws;
  u16* xb = (u16*)ws;                                               // 32 MB
  u16* bt = (u16*)(ws + (size_t)M * K * 2);                         // 8 MB
  float* dsum = (float*)(ws + (size_t)M * K * 2 + (size_t)N * K * 2);  // 16 KB
  unsigned* bar = (unsigned*)(dsum + K);                            // 2 counters

  // zero dsum + barrier counters (ws is poisoned 0xAA before every call)
  hipMemsetAsync(dsum, 0, K * sizeof(float) + 2 * sizeof(unsigned), stream);
  mega_kernel<<<dim3(NBLK), 256, 0, stream>>>(x, W, U, Tp, xb, bt, dsum, bar, out);
}